// Round 4
// baseline (487.941 us; speedup 1.0000x reference)
//
#include <hip/hip_runtime.h>
#include <hip/hip_bf16.h>

typedef _Float16 f16;
typedef _Float16 f16x8 __attribute__((ext_vector_type(8)));
typedef _Float16 f16x4 __attribute__((ext_vector_type(4)));
typedef float f32x4 __attribute__((ext_vector_type(4)));

#define MFMA16(a, b, c) __builtin_amdgcn_mfma_f32_16x16x32_f16(a, b, c, 0, 0, 0)

static constexpr int S  = 4096;
static constexpr int NB = 4;    // batches

// ---------------------------------------------------------------------------
// Weight convert + transpose: Wt[n][k] = (f16) W[k][n]   (256x256)
// ---------------------------------------------------------------------------
__global__ void wconv_kernel(const float* __restrict__ W, f16* __restrict__ Wt) {
    int k = blockIdx.x;      // 0..255
    int n = threadIdx.x;     // 0..255
    Wt[n * 256 + k] = (f16)W[k * 256 + n];
}

// ---------------------------------------------------------------------------
// Projection GEMM: O[m][n] = epilogue( sum_k A[m][k] * Wt[n][k] + bias[n] )
// M = 16384, N = 256, K = 256.  Block: 256 thr (4 waves), BM = 32 rows/block.
// ASRC: 0 = A is fp32 (convert on the fly), 1 = A is f16.
// OMODE: 0 = store f16 row-major; 1 = cos() then store f16 row-major;
//        2 = store f16 TRANSPOSED per batch: O[(bi*256 + n)*S + s]
// ---------------------------------------------------------------------------
template <int ASRC, int OMODE>
__global__ __launch_bounds__(256) void proj_kernel(
    const float* __restrict__ Af, const f16* __restrict__ Ah,
    const f16* __restrict__ Wt, const float* __restrict__ bias,
    f16* __restrict__ O)
{
    int mbase = blockIdx.x * 32;
    int tid = threadIdx.x;
    int w = tid >> 6, l = tid & 63;
    int lr = l & 15, lg = l >> 4;
    int nbase = w * 64;

    f32x4 acc[2][4];
#pragma unroll
    for (int mf = 0; mf < 2; ++mf)
#pragma unroll
        for (int nf = 0; nf < 4; ++nf) acc[mf][nf] = f32x4{0.f, 0.f, 0.f, 0.f};

#pragma unroll
    for (int ks = 0; ks < 8; ++ks) {
        int kof = ks * 32 + lg * 8;
        f16x8 a[2], b[4];
#pragma unroll
        for (int mf = 0; mf < 2; ++mf) {
            int row = mbase + mf * 16 + lr;
            if (ASRC == 0) {
                const float4* p = (const float4*)(Af + row * 256 + kof);
                float4 x0 = p[0], x1 = p[1];
                f16x8 t;
                t[0] = (f16)x0.x; t[1] = (f16)x0.y; t[2] = (f16)x0.z; t[3] = (f16)x0.w;
                t[4] = (f16)x1.x; t[5] = (f16)x1.y; t[6] = (f16)x1.z; t[7] = (f16)x1.w;
                a[mf] = t;
            } else {
                a[mf] = *(const f16x8*)(Ah + row * 256 + kof);
            }
        }
#pragma unroll
        for (int nf = 0; nf < 4; ++nf) {
            int col = nbase + nf * 16 + lr;
            b[nf] = *(const f16x8*)(Wt + col * 256 + kof);
        }
#pragma unroll
        for (int mf = 0; mf < 2; ++mf)
#pragma unroll
            for (int nf = 0; nf < 4; ++nf)
                acc[mf][nf] = MFMA16(a[mf], b[nf], acc[mf][nf]);
    }

    // epilogue. C/D layout: col = lane&15, row = (lane>>4)*4 + reg  [HW-verified]
#pragma unroll
    for (int mf = 0; mf < 2; ++mf) {
#pragma unroll
        for (int nf = 0; nf < 4; ++nf) {
            int col = nbase + nf * 16 + lr;
            float bv = bias[col];
            if (OMODE <= 1) {
#pragma unroll
                for (int r = 0; r < 4; ++r) {
                    int row = mbase + mf * 16 + lg * 4 + r;
                    float x = acc[mf][nf][r] + bv;
                    if (OMODE == 1) x = cosf(x);
                    O[row * 256 + col] = (f16)x;
                }
            } else {
                int bi = mbase >> 12;                       // S = 4096, BM=32 | S
                int s  = (mbase & (S - 1)) + mf * 16 + lg * 4;
                f16x4 v;
#pragma unroll
                for (int r = 0; r < 4; ++r) v[r] = (f16)(acc[mf][nf][r] + bv);
                *(f16x4*)(O + ((bi * 256 + col) * S + s)) = v;
            }
        }
    }
}

// ---------------------------------------------------------------------------
// Flash attention, 8 waves/block, OUTPUT-D SPLIT (keys shared).
//   Waves 0-3 (g=0): output d 0..127.  Waves 4-7 (g=1): d 128..255.
//   Wave wg in each group owns q-rows qbase + wg*16.  KBLK = 32, NT = 128.
//   K-hat tile: shared by all 8 waves, DOUBLE-buffered, XOR-swizzled
//     ([32][256] f16, chunk' = chunk16 ^ (row&7)) -> conflict-free b128 reads.
//   V^T tile: per-group half [128][36] f16, single-buffered, loads issued at
//     iteration start (latency hides under QK^T + softmax).
//   QK^T computed redundantly by both groups (identical softmax state) ->
//     no cross-group merge epilogue at all.
//   Softmax: defer-max (threshold 8), per-lane partial denom, end-only reduce.
// Grid: 256 blocks.  bid&7 -> XCD; batch b = (bid>>1)&3 pins to 2 XCDs.
// ---------------------------------------------------------------------------
__global__ __launch_bounds__(512, 2) void attn_kernel(
    const f16* __restrict__ Qf, const f16* __restrict__ Hf,
    const f16* __restrict__ Vt, float* __restrict__ Out)
{
    // LDS: KhS[2][32][256] f16 (32768) + VtS[2][128][36] f16 (18432)
    //      + PS[8][16][40] f16 (10240)  = 61440 B
    __shared__ __align__(16) char ldsp[61440];
    f16 (*KhS)[32][256] = (f16(*)[32][256])ldsp;
    f16 (*VtS)[128][36] = (f16(*)[128][36])(ldsp + 32768);
    f16 (*PS)[16][40]   = (f16(*)[16][40])(ldsp + 51200);

    int bid = blockIdx.x;
    int b   = (bid >> 1) & 3;
    int qi  = ((bid >> 3) << 1) | (bid & 1);
    int qbase = qi * 64;

    int tid = threadIdx.x;
    int w  = tid >> 6, l = tid & 63;
    int g  = w >> 2, wg = w & 3;
    int lr = l & 15, lg = l >> 4;
    int qb = qbase + wg * 16;
    int dbase = g * 128;

    // K-hat staging: 512 thr stage 32x256 tile (1024 x 16B chunks, 2/thread)
    int krow[2], kcol[2], kswz[2];
#pragma unroll
    for (int i = 0; i < 2; ++i) {
        int c = i * 512 + tid;
        krow[i] = c >> 5;
        int kc  = c & 31;
        kcol[i] = kc * 8;                        // global source (unswizzled)
        kswz[i] = (kc ^ (krow[i] & 7)) * 8;      // LDS dest (swizzled)
    }
    // V staging: per-group 256 thr stage V^T[dbase..+128][32] (512 chunks)
    int gt = tid & 255;
    int vrow[2], vc[2];
#pragma unroll
    for (int i = 0; i < 2; ++i) {
        int c = i * 256 + gt;
        vrow[i] = c >> 2;
        vc[i]   = c & 3;
    }

    // Q fragments for this wave's 16 rows (registers for all 128 tiles)
    f16x8 qf[8];
    {
        const f16* qp = Qf + (b * S + qb + lr) * 256 + lg * 8;
#pragma unroll
        for (int ks = 0; ks < 8; ++ks) qf[ks] = *(const f16x8*)(qp + ks * 32);
    }

    f32x4 Oacc[8];
#pragma unroll
    for (int i = 0; i < 8; ++i) Oacc[i] = f32x4{0.f, 0.f, 0.f, 0.f};
    float mrun[4], lsum[4];
#pragma unroll
    for (int r = 0; r < 4; ++r) { mrun[r] = -1e30f; lsum[r] = 0.f; }

    const f16* Hbase = Hf + b * S * 256;
    const f16* Vbase = Vt + b * 256 * S;

    // prologue: stage K-hat tile 0 into buffer 0 (swizzled)
#pragma unroll
    for (int i = 0; i < 2; ++i) {
        f16x8 v = *(const f16x8*)(Hbase + krow[i] * 256 + kcol[i]);
        *(f16x8*)&KhS[0][krow[i]][kswz[i]] = v;
    }
    __syncthreads();

    const int NT = S / 32;     // 128 key-tiles
    for (int t = 0; t < NT; ++t) {
        int cur = t & 1;
        int kt = t * 32;

        // issue loads early: V tile t (this group's d-half), K-hat tile t+1
        f16x8 rgV[2], rgK[2];
#pragma unroll
        for (int i = 0; i < 2; ++i)
            rgV[i] = *(const f16x8*)(Vbase + (size_t)(dbase + vrow[i]) * S + kt + vc[i] * 8);
        if (t + 1 < NT) {
#pragma unroll
            for (int i = 0; i < 2; ++i)
                rgK[i] = *(const f16x8*)(Hbase + (kt + 32 + krow[i]) * 256 + kcol[i]);
        }

        // scores: 16 q-rows x 32 keys, K=256  (swizzled K-hat reads)
        f32x4 scA[2], scB[2];
        scA[0] = f32x4{0.f,0.f,0.f,0.f}; scA[1] = f32x4{0.f,0.f,0.f,0.f};
        scB[0] = f32x4{0.f,0.f,0.f,0.f}; scB[1] = f32x4{0.f,0.f,0.f,0.f};
        __builtin_amdgcn_s_setprio(1);
#pragma unroll
        for (int ks = 0; ks < 8; ks += 2) {
#pragma unroll
            for (int nf = 0; nf < 2; ++nf) {
                int row = nf * 16 + lr;
                int sw  = row & 7;
                f16x8 kb0 = *(const f16x8*)&KhS[cur][row][((ks * 4 + lg) ^ sw) * 8];
                f16x8 kb1 = *(const f16x8*)&KhS[cur][row][((ks * 4 + 4 + lg) ^ sw) * 8];
                scA[nf] = MFMA16(qf[ks], kb0, scA[nf]);
                scB[nf] = MFMA16(qf[ks + 1], kb1, scB[nf]);
            }
        }
        __builtin_amdgcn_s_setprio(0);
        f32x4 sc[2];
        sc[0] = scA[0] + scB[0];
        sc[1] = scA[1] + scB[1];

        // ---- softmax, defer-max: no shuffles/rescale in steady state ----
        float mloc[4];
        int need = 0;
#pragma unroll
        for (int r = 0; r < 4; ++r) {
            mloc[r] = fmaxf(sc[0][r], sc[1][r]);
            need |= (mloc[r] > mrun[r] + 8.f) ? 1 : 0;
        }
        if (__any(need)) {        // rare: max grew past threshold
            float corr[4];
#pragma unroll
            for (int r = 0; r < 4; ++r) {
                float mt = mloc[r];
#pragma unroll
                for (int msk = 1; msk <= 8; msk <<= 1) mt = fmaxf(mt, __shfl_xor(mt, msk));
                float mn = fmaxf(mrun[r], mt);
                corr[r] = __expf(mrun[r] - mn);
                mrun[r] = mn;
                lsum[r] *= corr[r];
            }
#pragma unroll
            for (int i = 0; i < 8; ++i) {
                f32x4 o = Oacc[i];
                o[0] *= corr[0]; o[1] *= corr[1]; o[2] *= corr[2]; o[3] *= corr[3];
                Oacc[i] = o;
            }
        }
#pragma unroll
        for (int r = 0; r < 4; ++r) {
            float p0 = __expf(sc[0][r] - mrun[r]);   // bounded by e^8
            float p1 = __expf(sc[1][r] - mrun[r]);
            lsum[r] += p0 + p1;                      // per-lane partial denom
            PS[w][lg * 4 + r][lr]      = (f16)p0;
            PS[w][lg * 4 + r][16 + lr] = (f16)p1;
        }

        // commit V tile (loads issued at iter start; vmcnt mostly drained)
#pragma unroll
        for (int i = 0; i < 2; ++i)
            *(f16x8*)&VtS[g][vrow[i]][vc[i] * 8] = rgV[i];
        __syncthreads();          // VtS + PS visible; KhS[cur] fully read

        // ---- PV: Oacc[q][d] += P[q][key] * V^T[d][key], this d-half ----
        {
            f16x8 pa = *(const f16x8*)&PS[w][lr][lg * 8];
            __builtin_amdgcn_s_setprio(1);
#pragma unroll
            for (int nf2 = 0; nf2 < 8; ++nf2) {
                f16x8 vb = *(const f16x8*)&VtS[g][nf2 * 16 + lr][lg * 8];
                Oacc[nf2] = MFMA16(pa, vb, Oacc[nf2]);
            }
            __builtin_amdgcn_s_setprio(0);
        }

        // commit next K-hat tile into the other buffer (swizzled)
        if (t + 1 < NT) {
#pragma unroll
            for (int i = 0; i < 2; ++i)
                *(f16x8*)&KhS[cur ^ 1][krow[i]][kswz[i]] = rgK[i];
        }
        __syncthreads();          // KhS[cur^1] committed; VtS free next iter
    }

    // ---- epilogue: reduce denominators across the 16-lane key groups ----
    float inv[4];
#pragma unroll
    for (int r = 0; r < 4; ++r) {
        float s = lsum[r];
#pragma unroll
        for (int msk = 1; msk <= 8; msk <<= 1) s += __shfl_xor(s, msk);
        inv[r] = 1.0f / s;
    }
#pragma unroll
    for (int nf2 = 0; nf2 < 8; ++nf2) {
#pragma unroll
        for (int r = 0; r < 4; ++r) {
            int row = qb + lg * 4 + r;
            Out[(b * S + row) * 256 + dbase + nf2 * 16 + lr] = Oacc[nf2][r] * inv[r];
        }
    }
}

// ---------------------------------------------------------------------------
extern "C" void kernel_launch(void* const* d_in, const int* in_sizes, int n_in,
                              void* d_out, int out_size, void* d_ws, size_t ws_size,
                              hipStream_t stream)
{
    const float* query = (const float*)d_in[0];
    const float* value = (const float*)d_in[1];
    const float* Wq    = (const float*)d_in[2];
    const float* bq    = (const float*)d_in[3];
    const float* Wk    = (const float*)d_in[4];
    const float* bk    = (const float*)d_in[5];
    const float* Wv    = (const float*)d_in[6];
    const float* bv    = (const float*)d_in[7];
    const float* Wr    = (const float*)d_in[8];
    const float* br    = (const float*)d_in[9];
    float* out = (float*)d_out;

    char* ws = (char*)d_ws;
    size_t off = 0;
    auto alloc = [&](size_t bytes) -> char* {
        char* p = ws + off;
        off += (bytes + 255) & ~(size_t)255;
        return p;
    };
    f16* WqT = (f16*)alloc((size_t)65536 * 2);
    f16* WkT = (f16*)alloc((size_t)65536 * 2);
    f16* WvT = (f16*)alloc((size_t)65536 * 2);
    f16* WrT = (f16*)alloc((size_t)65536 * 2);
    f16* Qf  = (f16*)alloc((size_t)NB * S * 256 * 2);
    f16* Kf  = (f16*)alloc((size_t)NB * S * 256 * 2);
    f16* Hf  = (f16*)alloc((size_t)NB * S * 256 * 2);
    f16* VtF = (f16*)alloc((size_t)NB * S * 256 * 2);
    (void)ws_size; (void)in_sizes; (void)n_in; (void)out_size;

    wconv_kernel<<<256, 256, 0, stream>>>(Wq, WqT);
    wconv_kernel<<<256, 256, 0, stream>>>(Wk, WkT);
    wconv_kernel<<<256, 256, 0, stream>>>(Wv, WvT);
    wconv_kernel<<<256, 256, 0, stream>>>(Wr, WrT);

    // Q = query @ Wq + bq           (f16 row-major)
    proj_kernel<0, 0><<<512, 256, 0, stream>>>(query, nullptr, WqT, bq, Qf);
    // K = value @ Wk + bk           (f16 row-major)
    proj_kernel<0, 0><<<512, 256, 0, stream>>>(value, nullptr, WkT, bk, Kf);
    // Khat = cos(K @ Wr + br)       (f16 row-major)
    proj_kernel<1, 1><<<512, 256, 0, stream>>>(nullptr, Kf, WrT, br, Hf);
    // V^T = (value @ Wv + bv)^T     (f16, [b][d][s])
    proj_kernel<0, 2><<<512, 256, 0, stream>>>(value, nullptr, WvT, bv, VtF);

    // flash attention, output-d split (no merge kernel needed)
    attn_kernel<<<256, 512, 0, stream>>>(Qf, Hf, VtF, out);
}

// Round 5
// 213.145 us; speedup vs baseline: 2.2892x; 2.2892x over previous
//
#include <hip/hip_runtime.h>
#include <hip/hip_bf16.h>

typedef _Float16 f16;
typedef _Float16 f16x8 __attribute__((ext_vector_type(8)));
typedef _Float16 f16x4 __attribute__((ext_vector_type(4)));
typedef float f32x4 __attribute__((ext_vector_type(4)));

#define MFMA16(a, b, c) __builtin_amdgcn_mfma_f32_16x16x32_f16(a, b, c, 0, 0, 0)

static constexpr int S  = 4096;
static constexpr int NB = 4;    // batches

// ---------------------------------------------------------------------------
// Weight convert + transpose: Wt[n][k] = (f16) W[k][n]   (256x256)
// ---------------------------------------------------------------------------
__global__ void wconv_kernel(const float* __restrict__ W, f16* __restrict__ Wt) {
    int k = blockIdx.x;      // 0..255
    int n = threadIdx.x;     // 0..255
    Wt[n * 256 + k] = (f16)W[k * 256 + n];
}

// ---------------------------------------------------------------------------
// Projection GEMM: O[m][n] = epilogue( sum_k A[m][k] * Wt[n][k] + bias[n] )
// M = 16384, N = 256, K = 256.  Block: 256 thr (4 waves), BM = 32 rows/block.
// ASRC: 0 = A is fp32 (convert on the fly), 1 = A is f16.
// OMODE: 0 = store f16 row-major; 1 = cos() then store f16 row-major;
//        2 = store f16 TRANSPOSED per batch: O[(bi*256 + n)*S + s]
// ---------------------------------------------------------------------------
template <int ASRC, int OMODE>
__global__ __launch_bounds__(256) void proj_kernel(
    const float* __restrict__ Af, const f16* __restrict__ Ah,
    const f16* __restrict__ Wt, const float* __restrict__ bias,
    f16* __restrict__ O)
{
    int mbase = blockIdx.x * 32;
    int tid = threadIdx.x;
    int w = tid >> 6, l = tid & 63;
    int lr = l & 15, lg = l >> 4;
    int nbase = w * 64;

    f32x4 acc[2][4];
#pragma unroll
    for (int mf = 0; mf < 2; ++mf)
#pragma unroll
        for (int nf = 0; nf < 4; ++nf) acc[mf][nf] = f32x4{0.f, 0.f, 0.f, 0.f};

#pragma unroll
    for (int ks = 0; ks < 8; ++ks) {
        int kof = ks * 32 + lg * 8;
        f16x8 a[2], b[4];
#pragma unroll
        for (int mf = 0; mf < 2; ++mf) {
            int row = mbase + mf * 16 + lr;
            if (ASRC == 0) {
                const float4* p = (const float4*)(Af + row * 256 + kof);
                float4 x0 = p[0], x1 = p[1];
                f16x8 t;
                t[0] = (f16)x0.x; t[1] = (f16)x0.y; t[2] = (f16)x0.z; t[3] = (f16)x0.w;
                t[4] = (f16)x1.x; t[5] = (f16)x1.y; t[6] = (f16)x1.z; t[7] = (f16)x1.w;
                a[mf] = t;
            } else {
                a[mf] = *(const f16x8*)(Ah + row * 256 + kof);
            }
        }
#pragma unroll
        for (int nf = 0; nf < 4; ++nf) {
            int col = nbase + nf * 16 + lr;
            b[nf] = *(const f16x8*)(Wt + col * 256 + kof);
        }
#pragma unroll
        for (int mf = 0; mf < 2; ++mf)
#pragma unroll
            for (int nf = 0; nf < 4; ++nf)
                acc[mf][nf] = MFMA16(a[mf], b[nf], acc[mf][nf]);
    }

    // epilogue. C/D layout: col = lane&15, row = (lane>>4)*4 + reg  [HW-verified]
#pragma unroll
    for (int mf = 0; mf < 2; ++mf) {
#pragma unroll
        for (int nf = 0; nf < 4; ++nf) {
            int col = nbase + nf * 16 + lr;
            float bv = bias[col];
            if (OMODE <= 1) {
#pragma unroll
                for (int r = 0; r < 4; ++r) {
                    int row = mbase + mf * 16 + lg * 4 + r;
                    float x = acc[mf][nf][r] + bv;
                    if (OMODE == 1) x = cosf(x);
                    O[row * 256 + col] = (f16)x;
                }
            } else {
                int bi = mbase >> 12;                       // S = 4096, BM=32 | S
                int s  = (mbase & (S - 1)) + mf * 16 + lg * 4;
                f16x4 v;
#pragma unroll
                for (int r = 0; r < 4; ++r) v[r] = (f16)(acc[mf][nf][r] + bv);
                *(f16x4*)(O + ((bi * 256 + col) * S + s)) = v;
            }
        }
    }
}

// ---------------------------------------------------------------------------
// Flash attention, 8 waves/block, KBLK = 64, in-tile key split.
//   Waves 0-3 (g=0): keys 0..31 of each tile; waves 4-7 (g=1): keys 32..63.
//   Wave wg in each group owns q-rows qbase + wg*16.  NT = 64 iterations.
//   K-hat tile [64][264] f16 (pad +16B, 2-way-free banks), staged ONCE per
//     iter by all 512 threads, single-buffered with register prefetch.
//   V^T tile [256][72] f16 staged per iter (full 128-B rows), loads issued at
//     iteration start (hide under QK^T).
//   Softmax: defer-max (thr 8), per-lane partial denom, end-only reduce;
//   cross-group (m,l,O) merge via LDS overlay epilogue (round-3 proven).
// Grid: 256 blocks.  bid&7 -> XCD; batch b = (bid>>1)&3 pins to 2 XCDs.
// ---------------------------------------------------------------------------
__global__ __launch_bounds__(512, 1) void attn_kernel(
    const f16* __restrict__ Qf, const f16* __restrict__ Hf,
    const f16* __restrict__ Vt, float* __restrict__ Out)
{
    // loop phase:  KhS[64][264] f16 (33792) + VtS[256][72] f16 (36864)
    //              + PS[8][16][40] f16 (10240)              = 80896 B
    // epilogue overlay: MrgF[4][16][130] f32 (33280) + ML[8][16][2] f32
    __shared__ __align__(16) char ldsp[80896];
    f16 (*KhS)[264]       = (f16(*)[264])ldsp;
    f16 (*VtS)[72]        = (f16(*)[72])(ldsp + 33792);
    f16 (*PS)[16][40]     = (f16(*)[16][40])(ldsp + 70656);
    float (*MrgF)[16][130] = (float(*)[16][130])ldsp;
    float (*ML)[16][2]     = (float(*)[16][2])(ldsp + 33280);

    int bid = blockIdx.x;
    int b   = (bid >> 1) & 3;
    int qi  = ((bid >> 3) << 1) | (bid & 1);
    int qbase = qi * 64;

    int tid = threadIdx.x;
    int w  = tid >> 6, l = tid & 63;
    int g  = w >> 2, wg = w & 3;
    int lr = l & 15, lg = l >> 4;
    int qb = qbase + wg * 16;
    int kg = g * 32;              // this group's key offset within the tile

    // staging indices: 512 threads, 4 x 16B chunks each for K-hat and V
    int krow[4], kc[4], vrow[4], vc[4];
#pragma unroll
    for (int i = 0; i < 4; ++i) {
        int c = i * 512 + tid;
        krow[i] = c >> 5;  kc[i] = c & 31;    // K-hat: 64 rows x 32 chunks
        vrow[i] = c >> 3;  vc[i] = c & 7;     // V^T: 256 rows x 8 chunks
    }

    // Q fragments for this wave's 16 rows (registers for all 64 tiles)
    f16x8 qf[8];
    {
        const f16* qp = Qf + (b * S + qb + lr) * 256 + lg * 8;
#pragma unroll
        for (int ks = 0; ks < 8; ++ks) qf[ks] = *(const f16x8*)(qp + ks * 32);
    }

    f32x4 Oacc[16];
#pragma unroll
    for (int i = 0; i < 16; ++i) Oacc[i] = f32x4{0.f, 0.f, 0.f, 0.f};
    float mrun[4], lsum[4];
#pragma unroll
    for (int r = 0; r < 4; ++r) { mrun[r] = -1e30f; lsum[r] = 0.f; }

    const f16* Hbase = Hf + b * S * 256;
    const f16* Vbase = Vt + b * 256 * S;

    // prologue: stage K-hat tile 0
#pragma unroll
    for (int i = 0; i < 4; ++i) {
        f16x8 v = *(const f16x8*)(Hbase + krow[i] * 256 + kc[i] * 8);
        *(f16x8*)&KhS[krow[i]][kc[i] * 8] = v;
    }
    __syncthreads();

    const int NT = S / 64;     // 64 key-tiles of 64 keys
    for (int t = 0; t < NT; ++t) {
        int kt = t * 64;

        // issue loads early: V tile t, K-hat tile t+1
        f16x8 rgV[4], rgK[4];
#pragma unroll
        for (int i = 0; i < 4; ++i)
            rgV[i] = *(const f16x8*)(Vbase + (size_t)vrow[i] * S + kt + vc[i] * 8);
        if (t + 1 < NT) {
#pragma unroll
            for (int i = 0; i < 4; ++i)
                rgK[i] = *(const f16x8*)(Hbase + (kt + 64 + krow[i]) * 256 + kc[i] * 8);
        }

        // scores: 16 q-rows x this group's 32 keys, K=256
        f32x4 scA[2], scB[2];
        scA[0] = f32x4{0.f,0.f,0.f,0.f}; scA[1] = f32x4{0.f,0.f,0.f,0.f};
        scB[0] = f32x4{0.f,0.f,0.f,0.f}; scB[1] = f32x4{0.f,0.f,0.f,0.f};
        __builtin_amdgcn_s_setprio(1);
#pragma unroll
        for (int ks = 0; ks < 8; ks += 2) {
#pragma unroll
            for (int nf = 0; nf < 2; ++nf) {
                int row = kg + nf * 16 + lr;
                f16x8 kb0 = *(const f16x8*)&KhS[row][ks * 32 + lg * 8];
                f16x8 kb1 = *(const f16x8*)&KhS[row][(ks + 1) * 32 + lg * 8];
                scA[nf] = MFMA16(qf[ks], kb0, scA[nf]);
                scB[nf] = MFMA16(qf[ks + 1], kb1, scB[nf]);
            }
        }
        __builtin_amdgcn_s_setprio(0);
        f32x4 sc[2];
        sc[0] = scA[0] + scB[0];
        sc[1] = scA[1] + scB[1];

        // ---- softmax, defer-max: no shuffles/rescale in steady state ----
        float mloc[4];
        int need = 0;
#pragma unroll
        for (int r = 0; r < 4; ++r) {
            mloc[r] = fmaxf(sc[0][r], sc[1][r]);
            need |= (mloc[r] > mrun[r] + 8.f) ? 1 : 0;
        }
        if (__any(need)) {        // rare: max grew past threshold
            float corr[4];
#pragma unroll
            for (int r = 0; r < 4; ++r) {
                float mt = mloc[r];
#pragma unroll
                for (int msk = 1; msk <= 8; msk <<= 1) mt = fmaxf(mt, __shfl_xor(mt, msk));
                float mn = fmaxf(mrun[r], mt);
                corr[r] = __expf(mrun[r] - mn);
                mrun[r] = mn;
                lsum[r] *= corr[r];
            }
#pragma unroll
            for (int i = 0; i < 16; ++i) {
                f32x4 o = Oacc[i];
                o[0] *= corr[0]; o[1] *= corr[1]; o[2] *= corr[2]; o[3] *= corr[3];
                Oacc[i] = o;
            }
        }
#pragma unroll
        for (int r = 0; r < 4; ++r) {
            float p0 = __expf(sc[0][r] - mrun[r]);   // bounded by e^8
            float p1 = __expf(sc[1][r] - mrun[r]);
            lsum[r] += p0 + p1;                      // per-lane partial denom
            PS[w][lg * 4 + r][lr]      = (f16)p0;
            PS[w][lg * 4 + r][16 + lr] = (f16)p1;
        }

        __syncthreads();          // all QK reads of tile t done

        // commit V tile t; commit K-hat tile t+1 (loads issued ~600cy ago)
#pragma unroll
        for (int i = 0; i < 4; ++i)
            *(f16x8*)&VtS[vrow[i]][vc[i] * 8] = rgV[i];
        if (t + 1 < NT) {
#pragma unroll
            for (int i = 0; i < 4; ++i)
                *(f16x8*)&KhS[krow[i]][kc[i] * 8] = rgK[i];
        }
        __syncthreads();          // commits visible

        // ---- PV: Oacc[q][d] += P[q][key] * V^T[d][key], this key half ----
        {
            f16x8 pa = *(const f16x8*)&PS[w][lr][lg * 8];
            __builtin_amdgcn_s_setprio(1);
#pragma unroll
            for (int nf2 = 0; nf2 < 16; ++nf2) {
                f16x8 vb = *(const f16x8*)&VtS[nf2 * 16 + lr][kg + lg * 8];
                Oacc[nf2] = MFMA16(pa, vb, Oacc[nf2]);
            }
            __builtin_amdgcn_s_setprio(0);
        }
        // next iter's QK reads the K-hat tile committed above; its barrier A
        // guarantees this iter's PV finished reading VtS before overwrite.
    }

    // ---- epilogue: reduce denominators, merge the two key-groups ----
    float lrun[4];
#pragma unroll
    for (int r = 0; r < 4; ++r) {
        float s = lsum[r];
#pragma unroll
        for (int msk = 1; msk <= 8; msk <<= 1) s += __shfl_xor(s, msk);
        lrun[r] = s;
    }
    __syncthreads();              // loop LDS dead; safe to overlay

    if (lr == 0) {
#pragma unroll
        for (int r = 0; r < 4; ++r) {
            ML[w][lg * 4 + r][0] = mrun[r];
            ML[w][lg * 4 + r][1] = lrun[r];
        }
    }
    __syncthreads();

    float partM[4], partL[4];
#pragma unroll
    for (int r = 0; r < 4; ++r) {
        partM[r] = ML[w ^ 4][lg * 4 + r][0];
        partL[r] = ML[w ^ 4][lg * 4 + r][1];
    }
    float w0[4], w1[4];   // g0: w0 = e0*invd, w1 = invd.   g1: w1 = e1.
    if (g == 0) {
#pragma unroll
        for (int r = 0; r < 4; ++r) {
            float m  = fmaxf(mrun[r], partM[r]);
            float e0 = __expf(mrun[r] - m);
            float e1 = __expf(partM[r] - m);
            float invd = 1.0f / (lrun[r] * e0 + partL[r] * e1);
            w0[r] = e0 * invd;
            w1[r] = invd;
        }
    } else {
#pragma unroll
        for (int r = 0; r < 4; ++r) {
            float m = fmaxf(mrun[r], partM[r]);
            w1[r] = __expf(mrun[r] - m);
        }
    }

#pragma unroll
    for (int p = 0; p < 2; ++p) {
        if (g == 1) {
#pragma unroll
            for (int h = 0; h < 8; ++h) {
                int nf2 = p * 8 + h;
#pragma unroll
                for (int r = 0; r < 4; ++r)
                    MrgF[wg][lg * 4 + r][h * 16 + lr] = Oacc[nf2][r] * w1[r];
            }
        }
        __syncthreads();
        if (g == 0) {
#pragma unroll
            for (int h = 0; h < 8; ++h) {
                int nf2 = p * 8 + h;
#pragma unroll
                for (int r = 0; r < 4; ++r) {
                    float v = MrgF[wg][lg * 4 + r][h * 16 + lr];
                    int row = qb + lg * 4 + r;
                    Out[(b * S + row) * 256 + nf2 * 16 + lr] =
                        Oacc[nf2][r] * w0[r] + v * w1[r];
                }
            }
        }
        __syncthreads();
    }
}

// ---------------------------------------------------------------------------
extern "C" void kernel_launch(void* const* d_in, const int* in_sizes, int n_in,
                              void* d_out, int out_size, void* d_ws, size_t ws_size,
                              hipStream_t stream)
{
    const float* query = (const float*)d_in[0];
    const float* value = (const float*)d_in[1];
    const float* Wq    = (const float*)d_in[2];
    const float* bq    = (const float*)d_in[3];
    const float* Wk    = (const float*)d_in[4];
    const float* bk    = (const float*)d_in[5];
    const float* Wv    = (const float*)d_in[6];
    const float* bv    = (const float*)d_in[7];
    const float* Wr    = (const float*)d_in[8];
    const float* br    = (const float*)d_in[9];
    float* out = (float*)d_out;

    char* ws = (char*)d_ws;
    size_t off = 0;
    auto alloc = [&](size_t bytes) -> char* {
        char* p = ws + off;
        off += (bytes + 255) & ~(size_t)255;
        return p;
    };
    f16* WqT = (f16*)alloc((size_t)65536 * 2);
    f16* WkT = (f16*)alloc((size_t)65536 * 2);
    f16* WvT = (f16*)alloc((size_t)65536 * 2);
    f16* WrT = (f16*)alloc((size_t)65536 * 2);
    f16* Qf  = (f16*)alloc((size_t)NB * S * 256 * 2);
    f16* Kf  = (f16*)alloc((size_t)NB * S * 256 * 2);
    f16* Hf  = (f16*)alloc((size_t)NB * S * 256 * 2);
    f16* VtF = (f16*)alloc((size_t)NB * S * 256 * 2);
    (void)ws_size; (void)in_sizes; (void)n_in; (void)out_size;

    wconv_kernel<<<256, 256, 0, stream>>>(Wq, WqT);
    wconv_kernel<<<256, 256, 0, stream>>>(Wk, WkT);
    wconv_kernel<<<256, 256, 0, stream>>>(Wv, WvT);
    wconv_kernel<<<256, 256, 0, stream>>>(Wr, WrT);

    // Q = query @ Wq + bq           (f16 row-major)
    proj_kernel<0, 0><<<512, 256, 0, stream>>>(query, nullptr, WqT, bq, Qf);
    // K = value @ Wk + bk           (f16 row-major)
    proj_kernel<0, 0><<<512, 256, 0, stream>>>(value, nullptr, WkT, bk, Kf);
    // Khat = cos(K @ Wr + br)       (f16 row-major)
    proj_kernel<1, 1><<<512, 256, 0, stream>>>(nullptr, Kf, WrT, br, Hf);
    // V^T = (value @ Wv + bv)^T     (f16, [b][d][s])
    proj_kernel<0, 2><<<512, 256, 0, stream>>>(value, nullptr, WvT, bv, VtF);

    // flash attention, KBLK=64, in-tile key split + in-LDS merge
    attn_kernel<<<256, 512, 0, stream>>>(Qf, Hf, VtF, out);
}